// Round 1
// baseline (66526.721 us; speedup 1.0000x reference)
//
#include <hip/hip_runtime.h>
#include <stdint.h>

#define T_STEPS 2000
#define BATCH   64
#define HID     512

typedef __attribute__((ext_vector_type(8))) short bf16x8;
typedef __attribute__((ext_vector_type(4))) float f32x4;

__device__ __forceinline__ float bf2f(unsigned short s) {
  return __builtin_bit_cast(float, ((unsigned int)s) << 16);
}
__device__ __forceinline__ unsigned short f2bf(float f) {
  unsigned int u = __builtin_bit_cast(unsigned int, f);
  u = u + 0x7fffu + ((u >> 16) & 1u);   // RNE
  return (unsigned short)(u >> 16);
}
__device__ __forceinline__ float bflo(unsigned int u) { return __builtin_bit_cast(float, u << 16); }
__device__ __forceinline__ float bfhi(unsigned int u) { return __builtin_bit_cast(float, u & 0xffff0000u); }

// ---------------- fp32 -> bf16 conversion (4 elems/thread) ----------------
__global__ void cvt4_kernel(const float4* __restrict__ src, uint2* __restrict__ dst, long n4) {
  long i = (long)blockIdx.x * blockDim.x + threadIdx.x;
  if (i >= n4) return;
  float4 v = src[i];
  unsigned int lo = (unsigned int)f2bf(v.x) | ((unsigned int)f2bf(v.y) << 16);
  unsigned int hi = (unsigned int)f2bf(v.z) | ((unsigned int)f2bf(v.w) << 16);
  dst[i] = make_uint2(lo, hi);
}

// ------- pack recurrent weights: U[j][k] fp32 -> bf16 tiled so that -------
// ------- dst[kc*4096 + j*8 + ki] = U[j][kc*8+ki]  (perfectly coalesced) ---
__global__ void packU_kernel(const float* __restrict__ src, unsigned short* __restrict__ dst) {
  int i = blockIdx.x * blockDim.x + threadIdx.x;   // 0 .. 262143
  int j = i >> 9, k = i & 511;
  int kc = k >> 3, ki = k & 7;
  dst[(size_t)kc * 4096 + j * 8 + ki] = f2bf(src[i]);
}

// ---------------- input-projection GEMM: [M,512] x [512,1024] -------------
// A: bf16 row-major [M,512]. W: bf16 row-major [1024,512] (rows 0-511 = Wh,
// rows 512-1023 = Wz); computed as out[m,n] = sum_k A[m,k]*W[n,k] + bias[n].
__global__ __launch_bounds__(256) void gemm_proj(
    const unsigned short* __restrict__ A,
    const unsigned short* __restrict__ W,
    const float* __restrict__ bh, const float* __restrict__ bz,
    unsigned short* __restrict__ whb, unsigned short* __restrict__ wzb) {
  __shared__ unsigned short As[64 * 32];
  __shared__ unsigned short Bs[64 * 32];
  const int tid  = threadIdx.x;
  const int wave = tid >> 6, lane = tid & 63;
  const int quad = lane >> 4, l16 = lane & 15;
  const long m0 = (long)blockIdx.x * 64;
  const int  n0 = blockIdx.y * 64;
  const int  srow = tid >> 2, sk = (tid & 3) * 8;
  f32x4 acc0 = {0.f,0.f,0.f,0.f}, acc1 = {0.f,0.f,0.f,0.f};
  f32x4 acc2 = {0.f,0.f,0.f,0.f}, acc3 = {0.f,0.f,0.f,0.f};
  for (int k0 = 0; k0 < 512; k0 += 32) {
    *(uint4*)&As[srow * 32 + sk] = *(const uint4*)&A[(m0 + srow) * 512 + k0 + sk];
    *(uint4*)&Bs[srow * 32 + sk] = *(const uint4*)&W[(long)(n0 + srow) * 512 + k0 + sk];
    __syncthreads();
    bf16x8 a  = *(const bf16x8*)&As[(wave * 16 + l16) * 32 + quad * 8];
    bf16x8 b0 = *(const bf16x8*)&Bs[(0 * 16 + l16) * 32 + quad * 8];
    bf16x8 b1 = *(const bf16x8*)&Bs[(1 * 16 + l16) * 32 + quad * 8];
    bf16x8 b2 = *(const bf16x8*)&Bs[(2 * 16 + l16) * 32 + quad * 8];
    bf16x8 b3 = *(const bf16x8*)&Bs[(3 * 16 + l16) * 32 + quad * 8];
    acc0 = __builtin_amdgcn_mfma_f32_16x16x32_bf16(a, b0, acc0, 0, 0, 0);
    acc1 = __builtin_amdgcn_mfma_f32_16x16x32_bf16(a, b1, acc1, 0, 0, 0);
    acc2 = __builtin_amdgcn_mfma_f32_16x16x32_bf16(a, b2, acc2, 0, 0, 0);
    acc3 = __builtin_amdgcn_mfma_f32_16x16x32_bf16(a, b3, acc3, 0, 0, 0);
    __syncthreads();
  }
  // epilogue: whole block lives entirely in wh (n0<512) or wz region
  const float* bias = (n0 < 512) ? bh : bz;
  unsigned short* out = (n0 < 512) ? whb : wzb;
  const int nbase = (n0 < 512) ? n0 : (n0 - 512);
  f32x4 accs[4] = {acc0, acc1, acc2, acc3};
  #pragma unroll
  for (int jt = 0; jt < 4; ++jt) {
    int n = nbase + jt * 16 + l16;
    float bv = bias[n];
    #pragma unroll
    for (int r = 0; r < 4; ++r) {
      long m = m0 + wave * 16 + quad * 4 + r;   // C/D: row=(lane>>4)*4+reg, col=lane&15
      out[m * 512 + n] = f2bf(accs[jt][r] + bv);
    }
  }
}

// ---------------- sequential GRU scan: 1 workgroup per batch --------------
// 1024 threads: 2 threads per output unit (split-k). Thread (j = tid>>1,
// p = tid&1) accumulates over k in [256p, 256p+256); pair-reduce via
// __shfl_xor(.,1) (partner is the adjacent lane in the same wave).
// Uzp/Uhp: packed bf16 (see packU_kernel), read as uint4[kc*512 + j].
__global__ __launch_bounds__(1024, 4) void gru_scan(
    const unsigned short* __restrict__ whb, const unsigned short* __restrict__ wzb,
    const uint4* __restrict__ Uzp, const uint4* __restrict__ Uhp,
    unsigned short* __restrict__ out_bf, float* __restrict__ out_f32, int T) {
  const int b   = blockIdx.x;
  const int tid = threadIdx.x;
  const int j   = tid >> 1;          // output unit
  const int p   = tid & 1;           // k-half
  __shared__ float h[HID];
  __shared__ float g[HID];
  if (tid < HID) h[tid] = 0.f;
  __syncthreads();
  const uint4* __restrict__ Uzh = Uzp + (size_t)p * 32 * 512;  // this thread's k-half
  const uint4* __restrict__ Uhh = Uhp + (size_t)p * 32 * 512;
  const float* hp = h + p * 256;
  const float* gp = g + p * 256;
  for (int t = 0; t < T; ++t) {
    const long base = ((long)t * BATCH + b) * HID;
    // ---- phase 1: z = sigmoid(wz + h @ Uz^T) ----
    float a0 = 0.f, a1 = 0.f, a2 = 0.f, a3 = 0.f;
    #pragma unroll 8
    for (int kc = 0; kc < 32; ++kc) {
      uint4 u = Uzh[kc * 512 + j];
      const float4 ha = *(const float4*)&hp[kc * 8];
      const float4 hb2 = *(const float4*)&hp[kc * 8 + 4];
      a0 += bflo(u.x) * ha.x  + bfhi(u.x) * ha.y;
      a1 += bflo(u.y) * ha.z  + bfhi(u.y) * ha.w;
      a2 += bflo(u.z) * hb2.x + bfhi(u.z) * hb2.y;
      a3 += bflo(u.w) * hb2.z + bfhi(u.w) * hb2.w;
    }
    float a = (a0 + a1) + (a2 + a3);
    a += __shfl_xor(a, 1);
    float zpre = bf2f(wzb[base + j]) + a;
    float z = 1.f / (1.f + __expf(-zpre));
    float gj = z * h[j];
    if (p == 0) g[j] = gj;
    __syncthreads();
    // ---- phase 2: a = wh + (z*h) @ Uh^T ; h' = z*h + (1-z)*tanh(a) ----
    a0 = 0.f; a1 = 0.f; a2 = 0.f; a3 = 0.f;
    #pragma unroll 8
    for (int kc = 0; kc < 32; ++kc) {
      uint4 u = Uhh[kc * 512 + j];
      const float4 ga = *(const float4*)&gp[kc * 8];
      const float4 gb2 = *(const float4*)&gp[kc * 8 + 4];
      a0 += bflo(u.x) * ga.x  + bfhi(u.x) * ga.y;
      a1 += bflo(u.y) * ga.z  + bfhi(u.y) * ga.w;
      a2 += bflo(u.z) * gb2.x + bfhi(u.z) * gb2.y;
      a3 += bflo(u.w) * gb2.z + bfhi(u.w) * gb2.w;
    }
    a = (a0 + a1) + (a2 + a3);
    a += __shfl_xor(a, 1);
    if (p == 0) {
      float apre = bf2f(whb[base + j]) + a;
      float e  = __expf(-2.f * fabsf(apre));       // safe tanh (no inf/NaN)
      float th = copysignf((1.f - e) / (1.f + e), apre);
      float hn = gj + (1.f - z) * th;
      h[j] = hn;                                   // phase 2 reads only g -> safe
      if (out_bf) out_bf[base + j] = f2bf(hn);
      else        out_f32[base + j] = hn;
    }
    __syncthreads();
  }
}

extern "C" void kernel_launch(void* const* d_in, const int* in_sizes, int n_in,
                              void* d_out, int out_size, void* d_ws, size_t ws_size,
                              hipStream_t stream) {
  const float* x   = (const float*)d_in[0];
  const float* Wh0 = (const float*)d_in[1];
  const float* bh0 = (const float*)d_in[2];
  const float* Wz0 = (const float*)d_in[3];
  const float* bz0 = (const float*)d_in[4];
  const float* Uh0 = (const float*)d_in[5];
  const float* Uz0 = (const float*)d_in[6];
  const float* Wh1 = (const float*)d_in[7];
  const float* bh1 = (const float*)d_in[8];
  const float* Wz1 = (const float*)d_in[9];
  const float* bz1 = (const float*)d_in[10];
  const float* Uh1 = (const float*)d_in[11];
  const float* Uz1 = (const float*)d_in[12];
  float* out = (float*)d_out;

  const long TB = (long)T_STEPS * BATCH;   // 128000
  const long XN = TB * HID;                // 65,536,000 elements

  // ---- workspace layout (bf16 elements) ----
  unsigned short* p = (unsigned short*)d_ws;
  unsigned short* xb    = p; p += XN;
  unsigned short* wcat0 = p; p += 1024 * 512;
  unsigned short* wcat1 = p; p += 1024 * 512;
  unsigned short* uz0   = p; p += 512 * 512;
  unsigned short* uh0   = p; p += 512 * 512;
  unsigned short* uz1   = p; p += 512 * 512;
  unsigned short* uh1   = p; p += 512 * 512;
  unsigned short* whb   = p; p += XN;
  unsigned short* wzb   = p; p += XN;
  unsigned short* h0b   = p; p += XN;
  size_t need = (size_t)(p - (unsigned short*)d_ws) * sizeof(unsigned short);
  if (ws_size < need) return;   // insufficient workspace -> visible as absmax fail

  // ---- conversions ----
  auto cvt = [&](const float* s, unsigned short* d, long n) {
    long n4 = n / 4;
    int blocks = (int)((n4 + 255) / 256);
    hipLaunchKernelGGL(cvt4_kernel, dim3(blocks), dim3(256), 0, stream,
                       (const float4*)s, (uint2*)d, n4);
  };
  cvt(x,   xb,             XN);
  cvt(Wh0, wcat0,          512 * 512);
  cvt(Wz0, wcat0 + 262144, 512 * 512);
  cvt(Wh1, wcat1,          512 * 512);
  cvt(Wz1, wcat1 + 262144, 512 * 512);
  hipLaunchKernelGGL(packU_kernel, dim3(1024), dim3(256), 0, stream, Uz0, uz0);
  hipLaunchKernelGGL(packU_kernel, dim3(1024), dim3(256), 0, stream, Uh0, uh0);
  hipLaunchKernelGGL(packU_kernel, dim3(1024), dim3(256), 0, stream, Uz1, uz1);
  hipLaunchKernelGGL(packU_kernel, dim3(1024), dim3(256), 0, stream, Uh1, uh1);

  // ---- layer 0 ----
  hipLaunchKernelGGL(gemm_proj, dim3(2000, 16), dim3(256), 0, stream,
                     xb, wcat0, bh0, bz0, whb, wzb);
  hipLaunchKernelGGL(gru_scan, dim3(64), dim3(1024), 0, stream,
                     whb, wzb, (const uint4*)uz0, (const uint4*)uh0,
                     h0b, (float*)nullptr, T_STEPS);
  // ---- layer 1 ----
  hipLaunchKernelGGL(gemm_proj, dim3(2000, 16), dim3(256), 0, stream,
                     h0b, wcat1, bh1, bz1, whb, wzb);
  hipLaunchKernelGGL(gru_scan, dim3(64), dim3(1024), 0, stream,
                     whb, wzb, (const uint4*)uz1, (const uint4*)uh1,
                     (unsigned short*)nullptr, out, T_STEPS);
}

// Round 2
// 32514.185 us; speedup vs baseline: 2.0461x; 2.0461x over previous
//
#include <hip/hip_runtime.h>
#include <stdint.h>

#define T_STEPS 2000
#define BATCH   64
#define HID     512

typedef __attribute__((ext_vector_type(8))) _Float16 f16x8;
typedef __attribute__((ext_vector_type(2))) _Float16 f16x2;
typedef __attribute__((ext_vector_type(4))) float f32x4;

__device__ __forceinline__ unsigned short f2h(float f) {
  _Float16 h = (_Float16)f;                       // v_cvt_f16_f32, RNE
  return __builtin_bit_cast(unsigned short, h);
}
__device__ __forceinline__ float h2f(unsigned short s) {
  return (float)__builtin_bit_cast(_Float16, s);
}
__device__ __forceinline__ f16x2 u2h2(unsigned int u) {
  return __builtin_bit_cast(f16x2, u);
}

// v_dot2_f32_f16: acc += a.x*b.x + a.y*b.y  (fallback keeps correctness if
// the builtin is unavailable on this target)
#if __has_builtin(__builtin_amdgcn_fdot2)
#define FDOT2(a, b, c) __builtin_amdgcn_fdot2((a), (b), (c), false)
#else
#define FDOT2(a, b, c) ((c) + (float)(a).x * (float)(b).x + (float)(a).y * (float)(b).y)
#endif

// ---------------- fp32 -> f16 conversion (4 elems/thread) ----------------
__global__ void cvt4_kernel(const float4* __restrict__ src, uint2* __restrict__ dst, long n4) {
  long i = (long)blockIdx.x * blockDim.x + threadIdx.x;
  if (i >= n4) return;
  float4 v = src[i];
  unsigned int lo = (unsigned int)f2h(v.x) | ((unsigned int)f2h(v.y) << 16);
  unsigned int hi = (unsigned int)f2h(v.z) | ((unsigned int)f2h(v.w) << 16);
  dst[i] = make_uint2(lo, hi);
}

// ------- pack recurrent weights: U[j][k] fp32 -> f16 tiled so that --------
// ------- dst[kc*4096 + j*8 + ki] = U[j][kc*8+ki]  (perfectly coalesced) ---
__global__ void packU_kernel(const float* __restrict__ src, unsigned short* __restrict__ dst) {
  int i = blockIdx.x * blockDim.x + threadIdx.x;   // 0 .. 262143
  int j = i >> 9, k = i & 511;
  int kc = k >> 3, ki = k & 7;
  dst[(size_t)kc * 4096 + j * 8 + ki] = f2h(src[i]);
}

// ---------------- input-projection GEMM: [M,512] x [512,1024] -------------
// A: f16 row-major [M,512]. W: f16 row-major [1024,512] (rows 0-511 = Wh,
// rows 512-1023 = Wz); out[m,n] = sum_k A[m,k]*W[n,k] + bias[n].
__global__ __launch_bounds__(256) void gemm_proj(
    const unsigned short* __restrict__ A,
    const unsigned short* __restrict__ W,
    const float* __restrict__ bh, const float* __restrict__ bz,
    unsigned short* __restrict__ whb, unsigned short* __restrict__ wzb) {
  __shared__ unsigned short As[64 * 32];
  __shared__ unsigned short Bs[64 * 32];
  const int tid  = threadIdx.x;
  const int wave = tid >> 6, lane = tid & 63;
  const int quad = lane >> 4, l16 = lane & 15;
  const long m0 = (long)blockIdx.x * 64;
  const int  n0 = blockIdx.y * 64;
  const int  srow = tid >> 2, sk = (tid & 3) * 8;
  f32x4 acc0 = {0.f,0.f,0.f,0.f}, acc1 = {0.f,0.f,0.f,0.f};
  f32x4 acc2 = {0.f,0.f,0.f,0.f}, acc3 = {0.f,0.f,0.f,0.f};
  for (int k0 = 0; k0 < 512; k0 += 32) {
    *(uint4*)&As[srow * 32 + sk] = *(const uint4*)&A[(m0 + srow) * 512 + k0 + sk];
    *(uint4*)&Bs[srow * 32 + sk] = *(const uint4*)&W[(long)(n0 + srow) * 512 + k0 + sk];
    __syncthreads();
    f16x8 a  = *(const f16x8*)&As[(wave * 16 + l16) * 32 + quad * 8];
    f16x8 b0 = *(const f16x8*)&Bs[(0 * 16 + l16) * 32 + quad * 8];
    f16x8 b1 = *(const f16x8*)&Bs[(1 * 16 + l16) * 32 + quad * 8];
    f16x8 b2 = *(const f16x8*)&Bs[(2 * 16 + l16) * 32 + quad * 8];
    f16x8 b3 = *(const f16x8*)&Bs[(3 * 16 + l16) * 32 + quad * 8];
    acc0 = __builtin_amdgcn_mfma_f32_16x16x32_f16(a, b0, acc0, 0, 0, 0);
    acc1 = __builtin_amdgcn_mfma_f32_16x16x32_f16(a, b1, acc1, 0, 0, 0);
    acc2 = __builtin_amdgcn_mfma_f32_16x16x32_f16(a, b2, acc2, 0, 0, 0);
    acc3 = __builtin_amdgcn_mfma_f32_16x16x32_f16(a, b3, acc3, 0, 0, 0);
    __syncthreads();
  }
  // epilogue: whole block lives entirely in wh (n0<512) or wz region
  const float* bias = (n0 < 512) ? bh : bz;
  unsigned short* out = (n0 < 512) ? whb : wzb;
  const int nbase = (n0 < 512) ? n0 : (n0 - 512);
  f32x4 accs[4] = {acc0, acc1, acc2, acc3};
  #pragma unroll
  for (int jt = 0; jt < 4; ++jt) {
    int n = nbase + jt * 16 + l16;
    float bv = bias[n];
    #pragma unroll
    for (int r = 0; r < 4; ++r) {
      long m = m0 + wave * 16 + quad * 4 + r;   // C/D: row=(lane>>4)*4+reg, col=lane&15
      out[m * 512 + n] = f2h(accs[jt][r] + bv);
    }
  }
}

// ---------------- sequential GRU scan: 1 workgroup per batch --------------
// 512 threads, one output unit each. h/g stored in LDS as PACKED f16 so one
// ds_read_b128 broadcast yields 8 operands (half the LDS traffic of f32, all
// single-address broadcasts -> 0 bank conflicts). Inner dot uses
// v_dot2_f32_f16 (no per-element converts). Own-lane h/g stay in registers.
// Uzp/Uhp: packed f16 (see packU_kernel), read as uint4[kc*512 + j].
__global__ __launch_bounds__(512, 2) void gru_scan(
    const unsigned short* __restrict__ whb, const unsigned short* __restrict__ wzb,
    const uint4* __restrict__ Uzp, const uint4* __restrict__ Uhp,
    unsigned short* __restrict__ out_h16, float* __restrict__ out_f32, int T) {
  const int b = blockIdx.x;
  const int j = threadIdx.x;           // 0..511, one output unit per thread
  __shared__ alignas(16) _Float16 hs[HID];
  __shared__ alignas(16) _Float16 gs[HID];
  hs[j] = (_Float16)0.f;
  float hprev = 0.f;
  __syncthreads();
  const uint4* hs4 = (const uint4*)hs;
  const uint4* gs4 = (const uint4*)gs;
  for (int t = 0; t < T; ++t) {
    const long base = ((long)t * BATCH + b) * HID;
    // hoist the (HBM) wh/wz loads: latency hides under the phase-1 dot loop
    float wzv = h2f(wzb[base + j]);
    float whv = h2f(whb[base + j]);
    // ---- phase 1: z = sigmoid(wz + h @ Uz^T) ----
    float a0 = 0.f, a1 = 0.f, a2 = 0.f, a3 = 0.f;
    #pragma unroll 8
    for (int kc = 0; kc < 64; ++kc) {
      uint4 u  = Uzp[kc * 512 + j];
      uint4 hv = hs4[kc];                       // broadcast, 8 f16
      a0 = FDOT2(u2h2(u.x), u2h2(hv.x), a0);
      a1 = FDOT2(u2h2(u.y), u2h2(hv.y), a1);
      a2 = FDOT2(u2h2(u.z), u2h2(hv.z), a2);
      a3 = FDOT2(u2h2(u.w), u2h2(hv.w), a3);
    }
    float zpre = wzv + (a0 + a1) + (a2 + a3);
    float z = 1.f / (1.f + __expf(-zpre));
    float gj = z * hprev;
    gs[j] = (_Float16)gj;
    __syncthreads();
    // ---- phase 2: a = wh + (z*h) @ Uh^T ; h' = z*h + (1-z)*tanh(a) ----
    a0 = 0.f; a1 = 0.f; a2 = 0.f; a3 = 0.f;
    #pragma unroll 8
    for (int kc = 0; kc < 64; ++kc) {
      uint4 u  = Uhp[kc * 512 + j];
      uint4 gv = gs4[kc];                       // broadcast, 8 f16
      a0 = FDOT2(u2h2(u.x), u2h2(gv.x), a0);
      a1 = FDOT2(u2h2(u.y), u2h2(gv.y), a1);
      a2 = FDOT2(u2h2(u.z), u2h2(gv.z), a2);
      a3 = FDOT2(u2h2(u.w), u2h2(gv.w), a3);
    }
    float apre = whv + (a0 + a1) + (a2 + a3);
    float e  = __expf(-2.f * fabsf(apre));       // safe tanh (no inf/NaN)
    float th = copysignf((1.f - e) / (1.f + e), apre);
    float hn = gj + (1.f - z) * th;
    hprev = hn;
    hs[j] = (_Float16)hn;                        // phase 2 reads only gs -> safe
    if (out_h16) out_h16[base + j] = f2h(hn);
    else         out_f32[base + j] = hn;
    __syncthreads();
  }
}

extern "C" void kernel_launch(void* const* d_in, const int* in_sizes, int n_in,
                              void* d_out, int out_size, void* d_ws, size_t ws_size,
                              hipStream_t stream) {
  const float* x   = (const float*)d_in[0];
  const float* Wh0 = (const float*)d_in[1];
  const float* bh0 = (const float*)d_in[2];
  const float* Wz0 = (const float*)d_in[3];
  const float* bz0 = (const float*)d_in[4];
  const float* Uh0 = (const float*)d_in[5];
  const float* Uz0 = (const float*)d_in[6];
  const float* Wh1 = (const float*)d_in[7];
  const float* bh1 = (const float*)d_in[8];
  const float* Wz1 = (const float*)d_in[9];
  const float* bz1 = (const float*)d_in[10];
  const float* Uh1 = (const float*)d_in[11];
  const float* Uz1 = (const float*)d_in[12];
  float* out = (float*)d_out;

  const long TB = (long)T_STEPS * BATCH;   // 128000
  const long XN = TB * HID;                // 65,536,000 elements

  // ---- workspace layout (f16 elements) ----
  unsigned short* p = (unsigned short*)d_ws;
  unsigned short* xb    = p; p += XN;
  unsigned short* wcat0 = p; p += 1024 * 512;
  unsigned short* wcat1 = p; p += 1024 * 512;
  unsigned short* uz0   = p; p += 512 * 512;
  unsigned short* uh0   = p; p += 512 * 512;
  unsigned short* uz1   = p; p += 512 * 512;
  unsigned short* uh1   = p; p += 512 * 512;
  unsigned short* whb   = p; p += XN;
  unsigned short* wzb   = p; p += XN;
  unsigned short* h0b   = p; p += XN;
  size_t need = (size_t)(p - (unsigned short*)d_ws) * sizeof(unsigned short);
  if (ws_size < need) return;   // insufficient workspace -> visible as absmax fail

  // ---- conversions ----
  auto cvt = [&](const float* s, unsigned short* d, long n) {
    long n4 = n / 4;
    int blocks = (int)((n4 + 255) / 256);
    hipLaunchKernelGGL(cvt4_kernel, dim3(blocks), dim3(256), 0, stream,
                       (const float4*)s, (uint2*)d, n4);
  };
  cvt(x,   xb,             XN);
  cvt(Wh0, wcat0,          512 * 512);
  cvt(Wz0, wcat0 + 262144, 512 * 512);
  cvt(Wh1, wcat1,          512 * 512);
  cvt(Wz1, wcat1 + 262144, 512 * 512);
  hipLaunchKernelGGL(packU_kernel, dim3(1024), dim3(256), 0, stream, Uz0, uz0);
  hipLaunchKernelGGL(packU_kernel, dim3(1024), dim3(256), 0, stream, Uh0, uh0);
  hipLaunchKernelGGL(packU_kernel, dim3(1024), dim3(256), 0, stream, Uz1, uz1);
  hipLaunchKernelGGL(packU_kernel, dim3(1024), dim3(256), 0, stream, Uh1, uh1);

  // ---- layer 0 ----
  hipLaunchKernelGGL(gemm_proj, dim3(2000, 16), dim3(256), 0, stream,
                     xb, wcat0, bh0, bz0, whb, wzb);
  hipLaunchKernelGGL(gru_scan, dim3(64), dim3(512), 0, stream,
                     whb, wzb, (const uint4*)uz0, (const uint4*)uh0,
                     h0b, (float*)nullptr, T_STEPS);
  // ---- layer 1 ----
  hipLaunchKernelGGL(gemm_proj, dim3(2000, 16), dim3(256), 0, stream,
                     h0b, wcat1, bh1, bz1, whb, wzb);
  hipLaunchKernelGGL(gru_scan, dim3(64), dim3(512), 0, stream,
                     whb, wzb, (const uint4*)uz1, (const uint4*)uh1,
                     (unsigned short*)nullptr, out, T_STEPS);
}